// Round 1
// baseline (406.330 us; speedup 1.0000x reference)
//
#include <hip/hip_runtime.h>
#include <math.h>

#define H 768
#define NK 11
#define LN_EPS 1e-5f

__global__ __launch_bounds__(256) void geo_ln_kernel(
    const float* __restrict__ target,
    const float* __restrict__ boxes,
    const float* __restrict__ W,
    const float* __restrict__ bias,
    const float* __restrict__ gamma,
    const float* __restrict__ beta,
    float* __restrict__ out,
    int N)
{
    const int wave = threadIdx.x >> 6;
    const int lane = threadIdx.x & 63;
    const int box_id = blockIdx.x * 4 + wave;
    if (box_id >= N) return;

    // ---- target (uniform across all lanes) ----
    const float tx0 = target[0], ty0 = target[1], tx1 = target[2], ty1 = target[3];

    // ---- this wave's box (broadcast load, 16B aligned) ----
    const float4 bx = reinterpret_cast<const float4*>(boxes)[box_id];
    const float x0 = bx.x, y0 = bx.y, x1 = bx.z, y1 = bx.w;

    // ---- 11 geo features (computed redundantly per lane; ~60 VALU ops) ----
    float f[NK];
    const float w1 = tx1 - tx0, h1 = ty1 - ty0;
    const float w2 = x1 - x0,  h2 = y1 - y0;
    f[0] = w1; f[1] = h1; f[2] = w2; f[3] = h2;
    f[4] = fabsf(w1 - w2); f[5] = fabsf(h1 - h2);
    const float c1x = (tx0 + tx1) * 0.5f, c1y = (ty0 + ty1) * 0.5f;
    const float c2x = (x0 + x1) * 0.5f,  c2y = (y0 + y1) * 0.5f;
    const float dx = c2x - c1x, dy = c2y - c1y;
    f[6] = sqrtf(dx * dx + dy * dy);
    const bool overlap = (tx0 < x1) && (tx1 > x0) && (ty0 < y1) && (ty1 > y0);
    const float xi0 = fmaxf(tx0, x0), yi0 = fmaxf(ty0, y0);
    const float xi1 = fminf(tx1, x1), yi1 = fminf(ty1, y1);
    const float inter = overlap ? (xi1 - xi0) * (yi1 - yi0) : 0.0f;
    const float a1 = w1 * h1, a2 = w2 * h2;
    const float uni = a1 + a2 - inter;
    f[7] = inter / uni; f[8] = inter / a1; f[9] = inter / a2;
    const float degree = atan2f(fabsf(dy), fabsf(dx)) * 57.29577951308232f; // 180/pi
    // degree in [0, 90]: ref's nested where collapses to {<=22.5 -> 8, (22.5,67.5] -> 1, >67.5 -> 2}
    f[10] = (degree > 22.5f) ? ((degree > 67.5f) ? 2.0f : 1.0f) : 8.0f;

    // ---- x = f @ W + b for this lane's 12 columns (3 x float4, coalesced) ----
    const float4* __restrict__ W4 = reinterpret_cast<const float4*>(W);
    const float4* __restrict__ b4 = reinterpret_cast<const float4*>(bias);

    float4 xv[3];
    float s = 0.0f, sq = 0.0f;
    #pragma unroll
    for (int r = 0; r < 3; ++r) {
        const int c4 = lane + 64 * r;            // float4-column index, 0..191
        float4 acc = b4[c4];
        #pragma unroll
        for (int k = 0; k < NK; ++k) {
            const float4 w = W4[k * (H / 4) + c4];
            acc.x = fmaf(f[k], w.x, acc.x);
            acc.y = fmaf(f[k], w.y, acc.y);
            acc.z = fmaf(f[k], w.z, acc.z);
            acc.w = fmaf(f[k], w.w, acc.w);
        }
        xv[r] = acc;
        s  += acc.x + acc.y + acc.z + acc.w;
        sq += acc.x * acc.x + acc.y * acc.y + acc.z * acc.z + acc.w * acc.w;
    }

    // ---- wave-wide reduction (64 lanes, butterfly) ----
    #pragma unroll
    for (int off = 32; off >= 1; off >>= 1) {
        s  += __shfl_xor(s,  off, 64);
        sq += __shfl_xor(sq, off, 64);
    }
    const float mean = s * (1.0f / H);
    const float var  = sq * (1.0f / H) - mean * mean;
    const float rstd = rsqrtf(var + LN_EPS);

    // ---- normalize + affine + relu, coalesced float4 stores ----
    const float4* __restrict__ g4  = reinterpret_cast<const float4*>(gamma);
    const float4* __restrict__ be4 = reinterpret_cast<const float4*>(beta);
    float4* __restrict__ out4 = reinterpret_cast<float4*>(out) + (size_t)box_id * (H / 4);

    #pragma unroll
    for (int r = 0; r < 3; ++r) {
        const int c4 = lane + 64 * r;
        const float4 g = g4[c4];
        const float4 be = be4[c4];
        const float4 v = xv[r];
        float4 o;
        o.x = fmaxf(0.0f, (v.x - mean) * rstd * g.x + be.x);
        o.y = fmaxf(0.0f, (v.y - mean) * rstd * g.y + be.y);
        o.z = fmaxf(0.0f, (v.z - mean) * rstd * g.z + be.z);
        o.w = fmaxf(0.0f, (v.w - mean) * rstd * g.w + be.w);
        out4[c4] = o;
    }
}

extern "C" void kernel_launch(void* const* d_in, const int* in_sizes, int n_in,
                              void* d_out, int out_size, void* d_ws, size_t ws_size,
                              hipStream_t stream) {
    const float* target = (const float*)d_in[0];
    const float* boxes  = (const float*)d_in[1];
    const float* W      = (const float*)d_in[2];
    const float* bias   = (const float*)d_in[3];
    const float* gamma  = (const float*)d_in[4];
    const float* beta   = (const float*)d_in[5];
    float* out = (float*)d_out;

    const int N = in_sizes[1] / 4;           // ocr_boxes is (N, 4)
    const int boxes_per_block = 4;           // 4 waves x 64 lanes
    const int grid = (N + boxes_per_block - 1) / boxes_per_block;

    geo_ln_kernel<<<grid, 256, 0, stream>>>(target, boxes, W, bias, gamma, beta, out, N);
}

// Round 2
// 371.940 us; speedup vs baseline: 1.0925x; 1.0925x over previous
//
#include <hip/hip_runtime.h>
#include <math.h>

#define H 768
#define LN_EPS 1e-5f

// One wave (64 lanes) processes a stream of boxes. Each lane owns 12 output
// columns as 3 float4 (c4 = lane + 64r). W rows 2..10 live in registers
// (loaded once per wave); W rows 0,1 fold into `base` since f[0]=w1, f[1]=h1
// are constants of the launch (target box). FP op order matches the round-1
// kernel exactly (base = b + w1*W0 + h1*W1, then fma rows 2..10 in order).
__global__ __launch_bounds__(256) void geo_ln_kernel(
    const float* __restrict__ target,
    const float* __restrict__ boxes,
    const float* __restrict__ W,
    const float* __restrict__ bias,
    const float* __restrict__ gamma,
    const float* __restrict__ beta,
    float* __restrict__ out,
    int N)
{
    const int lane = threadIdx.x & 63;
    const int wid  = (blockIdx.x << 2) | (threadIdx.x >> 6);  // global wave id
    const int nw   = gridDim.x << 2;                          // total waves

    // ---- launch-constant target quantities ----
    const float tx0 = target[0], ty0 = target[1], tx1 = target[2], ty1 = target[3];
    const float w1 = tx1 - tx0, h1 = ty1 - ty0;
    const float c1x = (tx0 + tx1) * 0.5f, c1y = (ty0 + ty1) * 0.5f;
    const float a1 = w1 * h1;

    const float4* __restrict__ W4  = reinterpret_cast<const float4*>(W);
    const float4* __restrict__ b4  = reinterpret_cast<const float4*>(bias);
    const float4* __restrict__ g4  = reinterpret_cast<const float4*>(gamma);
    const float4* __restrict__ be4 = reinterpret_cast<const float4*>(beta);
    const float4* __restrict__ boxes4 = reinterpret_cast<const float4*>(boxes);
    float4* __restrict__ out4 = reinterpret_cast<float4*>(out);

    // ---- per-lane resident state: base (b + w1*W0 + h1*W1), W rows 2..10, gamma, beta ----
    float4 base[3], Wr[3][9], gm[3], bt[3];
    #pragma unroll
    for (int r = 0; r < 3; ++r) {
        const int c4 = lane + 64 * r;
        float4 acc = b4[c4];
        const float4 w0 = W4[0 * (H / 4) + c4];
        const float4 w1r = W4[1 * (H / 4) + c4];
        acc.x = fmaf(w1, w0.x, acc.x); acc.y = fmaf(w1, w0.y, acc.y);
        acc.z = fmaf(w1, w0.z, acc.z); acc.w = fmaf(w1, w0.w, acc.w);
        acc.x = fmaf(h1, w1r.x, acc.x); acc.y = fmaf(h1, w1r.y, acc.y);
        acc.z = fmaf(h1, w1r.z, acc.z); acc.w = fmaf(h1, w1r.w, acc.w);
        base[r] = acc;
        #pragma unroll
        for (int k = 0; k < 9; ++k)
            Wr[r][k] = W4[(k + 2) * (H / 4) + c4];
        gm[r] = g4[c4];
        bt[r] = be4[c4];
    }

    // ---- box loop ----
    for (int box = wid; box < N; box += nw) {
        const float4 bx = boxes4[box];
        const float x0 = bx.x, y0 = bx.y, x1 = bx.z, y1 = bx.w;

        // varying features: rows 2..10 of the feature vector
        float v[9];
        const float w2 = x1 - x0, h2 = y1 - y0;
        v[0] = w2; v[1] = h2;
        v[2] = fabsf(w1 - w2); v[3] = fabsf(h1 - h2);
        const float c2x = (x0 + x1) * 0.5f, c2y = (y0 + y1) * 0.5f;
        const float dx = c2x - c1x, dy = c2y - c1y;
        v[4] = sqrtf(dx * dx + dy * dy);
        const bool overlap = (tx0 < x1) && (tx1 > x0) && (ty0 < y1) && (ty1 > y0);
        const float xi0 = fmaxf(tx0, x0), yi0 = fmaxf(ty0, y0);
        const float xi1 = fminf(tx1, x1), yi1 = fminf(ty1, y1);
        const float inter = overlap ? (xi1 - xi0) * (yi1 - yi0) : 0.0f;
        const float a2 = w2 * h2;
        const float uni = a1 + a2 - inter;
        v[5] = inter / uni; v[6] = inter / a1; v[7] = inter / a2;
        const float degree = atan2f(fabsf(dy), fabsf(dx)) * 57.29577951308232f;
        v[8] = (degree > 22.5f) ? ((degree > 67.5f) ? 2.0f : 1.0f) : 8.0f;

        // x = base + sum_k v[k] * Wr[k]  (per-lane 12 columns)
        float4 xv[3];
        float s = 0.0f, sq = 0.0f;
        #pragma unroll
        for (int r = 0; r < 3; ++r) {
            float4 acc = base[r];
            #pragma unroll
            for (int k = 0; k < 9; ++k) {
                const float4 w = Wr[r][k];
                acc.x = fmaf(v[k], w.x, acc.x);
                acc.y = fmaf(v[k], w.y, acc.y);
                acc.z = fmaf(v[k], w.z, acc.z);
                acc.w = fmaf(v[k], w.w, acc.w);
            }
            xv[r] = acc;
            s  += acc.x + acc.y + acc.z + acc.w;
            sq += acc.x * acc.x + acc.y * acc.y + acc.z * acc.z + acc.w * acc.w;
        }

        // wave-wide butterfly reduction over 64 lanes
        #pragma unroll
        for (int off = 32; off >= 1; off >>= 1) {
            s  += __shfl_xor(s,  off, 64);
            sq += __shfl_xor(sq, off, 64);
        }
        const float mean = s * (1.0f / H);
        const float var  = sq * (1.0f / H) - mean * mean;
        const float rstd = rsqrtf(var + LN_EPS);

        // normalize + affine + relu; coalesced float4 stores
        float4* __restrict__ orow = out4 + (size_t)box * (H / 4);
        #pragma unroll
        for (int r = 0; r < 3; ++r) {
            const float4 vx = xv[r];
            const float4 g = gm[r], be = bt[r];
            float4 o;
            o.x = fmaxf(0.0f, (vx.x - mean) * rstd * g.x + be.x);
            o.y = fmaxf(0.0f, (vx.y - mean) * rstd * g.y + be.y);
            o.z = fmaxf(0.0f, (vx.z - mean) * rstd * g.z + be.z);
            o.w = fmaxf(0.0f, (vx.w - mean) * rstd * g.w + be.w);
            orow[lane + 64 * r] = o;
        }
    }
}

extern "C" void kernel_launch(void* const* d_in, const int* in_sizes, int n_in,
                              void* d_out, int out_size, void* d_ws, size_t ws_size,
                              hipStream_t stream) {
    const float* target = (const float*)d_in[0];
    const float* boxes  = (const float*)d_in[1];
    const float* W      = (const float*)d_in[2];
    const float* bias   = (const float*)d_in[3];
    const float* gamma  = (const float*)d_in[4];
    const float* beta   = (const float*)d_in[5];
    float* out = (float*)d_out;

    const int N = in_sizes[1] / 4;   // ocr_boxes is (N, 4)
    // 512 blocks x 4 waves = 2048 waves; each wave loads W once and streams
    // ~49 boxes. More blocks would re-read W per wave for no benefit.
    const int grid = 512;

    geo_ln_kernel<<<grid, 256, 0, stream>>>(target, boxes, W, bias, gamma, beta, out, N);
}

// Round 4
// 351.142 us; speedup vs baseline: 1.1572x; 1.0592x over previous
//
#include <hip/hip_runtime.h>
#include <math.h>

#define H 768
#define LN_EPS 1e-5f

typedef float nfloat4 __attribute__((ext_vector_type(4)));  // native vec for nontemporal store

// One wave = 64 lanes; each lane owns 12 output columns (3 x float4,
// c4 = lane + 64r). W rows 2..10 resident in registers (108 VGPRs), rows 0,1
// folded into `base` (target w1,h1 are launch constants). Two boxes in
// flight per iteration for ILP (weights shared).
// Bucket via tan-threshold compares: degree in [0,90] =>
//   <=22.5 -> 8, (22.5,67.5] -> 1, >67.5 -> 2;  degree > T <=> |dy| > |dx|*tan(T)
//   (same strict-inequality semantics incl. atan2(0,0)=0 -> 8).
__global__ __launch_bounds__(256, 2) void geo_ln_kernel(
    const float* __restrict__ target,
    const float* __restrict__ boxes,
    const float* __restrict__ W,
    const float* __restrict__ bias,
    const float* __restrict__ gamma,
    const float* __restrict__ beta,
    float* __restrict__ out,
    int N)
{
    const int lane = threadIdx.x & 63;
    const int wid  = (blockIdx.x << 2) | (threadIdx.x >> 6);  // global wave id
    const int nw   = gridDim.x << 2;                          // total waves

    // ---- launch-constant target quantities ----
    const float tx0 = target[0], ty0 = target[1], tx1 = target[2], ty1 = target[3];
    const float w1 = tx1 - tx0, h1 = ty1 - ty0;
    const float c1x = (tx0 + tx1) * 0.5f, c1y = (ty0 + ty1) * 0.5f;
    const float a1 = w1 * h1;
    const float ra1 = 1.0f / a1;                   // uniform, exact, hoisted
    const float tanA = 0.41421356237309503f;       // tan(22.5 deg)
    const float tanB = 2.41421356237309503f;       // tan(67.5 deg)

    const float4* __restrict__ W4  = reinterpret_cast<const float4*>(W);
    const float4* __restrict__ b4  = reinterpret_cast<const float4*>(bias);
    const float4* __restrict__ g4  = reinterpret_cast<const float4*>(gamma);
    const float4* __restrict__ be4 = reinterpret_cast<const float4*>(beta);
    const float4* __restrict__ boxes4 = reinterpret_cast<const float4*>(boxes);
    nfloat4* __restrict__ outv = reinterpret_cast<nfloat4*>(out);

    // ---- per-lane resident state ----
    float4 base[3], Wr[3][9], gm[3], bt[3];
    #pragma unroll
    for (int r = 0; r < 3; ++r) {
        const int c4 = lane + 64 * r;
        float4 acc = b4[c4];
        const float4 w0 = W4[0 * (H / 4) + c4];
        const float4 w1r = W4[1 * (H / 4) + c4];
        acc.x = fmaf(w1, w0.x, acc.x); acc.y = fmaf(w1, w0.y, acc.y);
        acc.z = fmaf(w1, w0.z, acc.z); acc.w = fmaf(w1, w0.w, acc.w);
        acc.x = fmaf(h1, w1r.x, acc.x); acc.y = fmaf(h1, w1r.y, acc.y);
        acc.z = fmaf(h1, w1r.z, acc.z); acc.w = fmaf(h1, w1r.w, acc.w);
        base[r] = acc;
        #pragma unroll
        for (int k = 0; k < 9; ++k)
            Wr[r][k] = W4[(k + 2) * (H / 4) + c4];
        gm[r] = g4[c4];
        bt[r] = be4[c4];
    }

    // ---- one-box body ----
    auto process = [&](int box) {
        const float4 bx = boxes4[box];
        const float x0 = bx.x, y0 = bx.y, x1 = bx.z, y1 = bx.w;

        float v[9];
        const float w2 = x1 - x0, h2 = y1 - y0;
        v[0] = w2; v[1] = h2;
        v[2] = fabsf(w1 - w2); v[3] = fabsf(h1 - h2);
        const float c2x = (x0 + x1) * 0.5f, c2y = (y0 + y1) * 0.5f;
        const float dx = c2x - c1x, dy = c2y - c1y;
        v[4] = __builtin_amdgcn_sqrtf(dx * dx + dy * dy);
        const bool overlap = (tx0 < x1) && (tx1 > x0) && (ty0 < y1) && (ty1 > y0);
        const float xi0 = fmaxf(tx0, x0), yi0 = fmaxf(ty0, y0);
        const float xi1 = fminf(tx1, x1), yi1 = fminf(ty1, y1);
        const float inter = overlap ? (xi1 - xi0) * (yi1 - yi0) : 0.0f;
        const float a2 = w2 * h2;
        const float uni = a1 + a2 - inter;
        v[5] = inter * __builtin_amdgcn_rcpf(uni);
        v[6] = inter * ra1;
        v[7] = inter * __builtin_amdgcn_rcpf(a2);
        const float adx = fabsf(dx), ady = fabsf(dy);
        v[8] = (ady > adx * tanA) ? ((ady > adx * tanB) ? 2.0f : 1.0f) : 8.0f;

        float4 xv[3];
        float s = 0.0f, sq = 0.0f;
        #pragma unroll
        for (int r = 0; r < 3; ++r) {
            float4 acc = base[r];
            #pragma unroll
            for (int k = 0; k < 9; ++k) {
                const float4 w = Wr[r][k];
                acc.x = fmaf(v[k], w.x, acc.x);
                acc.y = fmaf(v[k], w.y, acc.y);
                acc.z = fmaf(v[k], w.z, acc.z);
                acc.w = fmaf(v[k], w.w, acc.w);
            }
            xv[r] = acc;
            s  += acc.x + acc.y + acc.z + acc.w;
            sq += acc.x * acc.x + acc.y * acc.y + acc.z * acc.z + acc.w * acc.w;
        }

        #pragma unroll
        for (int off = 32; off >= 1; off >>= 1) {
            s  += __shfl_xor(s,  off, 64);
            sq += __shfl_xor(sq, off, 64);
        }
        const float mean = s * (1.0f / H);
        const float var  = sq * (1.0f / H) - mean * mean;
        const float rstd = __builtin_amdgcn_rsqf(var + LN_EPS);

        nfloat4* __restrict__ orow = outv + (size_t)box * (H / 4);
        #pragma unroll
        for (int r = 0; r < 3; ++r) {
            const float4 vx = xv[r];
            const float4 g = gm[r], be = bt[r];
            nfloat4 o;
            o.x = fmaxf(0.0f, (vx.x - mean) * rstd * g.x + be.x);
            o.y = fmaxf(0.0f, (vx.y - mean) * rstd * g.y + be.y);
            o.z = fmaxf(0.0f, (vx.z - mean) * rstd * g.z + be.z);
            o.w = fmaxf(0.0f, (vx.w - mean) * rstd * g.w + be.w);
            __builtin_nontemporal_store(o, &orow[lane + 64 * r]);
        }
    };

    // ---- box loop: two boxes in flight ----
    int box = wid;
    for (; box + nw < N; box += 2 * nw) {
        process(box);
        process(box + nw);
    }
    if (box < N) process(box);
}

extern "C" void kernel_launch(void* const* d_in, const int* in_sizes, int n_in,
                              void* d_out, int out_size, void* d_ws, size_t ws_size,
                              hipStream_t stream) {
    const float* target = (const float*)d_in[0];
    const float* boxes  = (const float*)d_in[1];
    const float* W      = (const float*)d_in[2];
    const float* bias   = (const float*)d_in[3];
    const float* gamma  = (const float*)d_in[4];
    const float* beta   = (const float*)d_in[5];
    float* out = (float*)d_out;

    const int N = in_sizes[1] / 4;   // ocr_boxes is (N, 4)
    // 512 blocks x 4 waves = 2048 waves; each wave loads W once, streams ~49 boxes.
    const int grid = 512;

    geo_ln_kernel<<<grid, 256, 0, stream>>>(target, boxes, W, bias, gamma, beta, out, N);
}